// Round 1
// baseline (185.660 us; speedup 1.0000x reference)
//
#include <hip/hip_runtime.h>
#include <hip/hip_cooperative_groups.h>
#include <cstdint>

namespace cg = cooperative_groups;

#define BATCH 8
#define CIN 64
#define COUT 128
#define HH 32
#define WW 32
#define PH 34   // padded H
#define PW 34   // padded W

typedef int v4i __attribute__((ext_vector_type(4)));
typedef float v4f __attribute__((ext_vector_type(4)));

// ---------------- workspace layout (fused kernel) ----------------
// f32[16..527]  : x absmax partials (512 blocks)
// f32[544..615] : w absmax partials (72 blocks)
// byte 4096     : xpad  int8 NHWC-padded [8,34,34,64] = 591872 B
// byte 595968   : wfrag int8 MFMA-B-swizzled [9][8][64][16] = 73728 B
#define WS_PX 16
#define WS_PW 544
#define XPAD_OFF 4096
#define WFRAG_OFF (4096 + BATCH * PH * PW * CIN)

__device__ __forceinline__ unsigned quantb(float v, float scale) {
    float q = rintf(v * scale);
    q = fminf(fmaxf(q, -128.0f), 127.0f);
    return ((unsigned)(int)q) & 255u;
}

// =====================================================================
// Fused single-launch cooperative kernel: 512 blocks x 256 threads
// (2 blocks/CU, co-resident). Phases separated by grid.sync().
// =====================================================================
__global__ __launch_bounds__(256, 2)
void fused_all(const float* __restrict__ x, const float* __restrict__ w,
               const float* __restrict__ bias,
               const float* __restrict__ Tf_in, const float* __restrict__ Tw_in,
               float* __restrict__ ws_f32, uint8_t* __restrict__ xpad,
               uint8_t* __restrict__ wfrag, float* __restrict__ out) {
    cg::grid_group grid = cg::this_grid();
    int blk = blockIdx.x;
    int t = threadIdx.x;
    int lane = t & 63;
    int wave = t >> 6;

    __shared__ unsigned lds[CIN * 9];   // 2304 B, reused across phases
    float* sf = (float*)lds;

    // ---------------- phase 1: absmax partials ----------------
    {
        // x: 2 MB = 131072 float4 = 512 blocks * 256 threads * 1
        const float4* x4 = (const float4*)x;
        float4 v = x4[blk * 256 + t];
        float mx = fmaxf(fmaxf(fabsf(v.x), fabsf(v.y)), fmaxf(fabsf(v.z), fabsf(v.w)));
        // w: 73728 floats = 18432 float4 = 72 blocks * 256 threads * 1
        float mw = 0.0f;
        if (blk < 72) {
            const float4* w4 = (const float4*)w;
            float4 u = w4[blk * 256 + t];
            mw = fmaxf(fmaxf(fabsf(u.x), fabsf(u.y)), fmaxf(fabsf(u.z), fabsf(u.w)));
        }
        #pragma unroll
        for (int off = 32; off > 0; off >>= 1) {
            mx = fmaxf(mx, __shfl_xor(mx, off, 64));
            mw = fmaxf(mw, __shfl_xor(mw, off, 64));
        }
        if (lane == 0) { sf[wave] = mx; sf[4 + wave] = mw; }
        __syncthreads();
        if (t == 0) {
            ws_f32[WS_PX + blk] = fmaxf(fmaxf(sf[0], sf[1]), fmaxf(sf[2], sf[3]));
            if (blk < 72)
                ws_f32[WS_PW + blk] = fmaxf(fmaxf(sf[4], sf[5]), fmaxf(sf[6], sf[7]));
        }
    }

    grid.sync();

    // ---------------- phase 1.5: every block reduces partials -> Tf, Tw in regs ----
    float Tf, Tw;
    {
        float mx = fmaxf(ws_f32[WS_PX + t], ws_f32[WS_PX + 256 + t]);
        float mw = (t < 72) ? ws_f32[WS_PW + t] : 0.0f;
        #pragma unroll
        for (int off = 32; off > 0; off >>= 1) {
            mx = fmaxf(mx, __shfl_xor(mx, off, 64));
            mw = fmaxf(mw, __shfl_xor(mw, off, 64));
        }
        if (lane == 0) { sf[wave] = mx; sf[4 + wave] = mw; }
        __syncthreads();
        float Mx = fmaxf(fmaxf(sf[0], sf[1]), fmaxf(sf[2], sf[3]));
        float Mw = fmaxf(fmaxf(sf[4], sf[5]), fmaxf(sf[6], sf[7]));
        Tf = 0.95f * Tf_in[0] + 0.05f * Mx;
        Tw = 0.95f * Tw_in[0] + 0.05f * Mw;
        __syncthreads();   // sf dead before lds reuse below
    }

    // ---------------- phase 2: quantize + pack + border zero-fill ----------------
    if (blk < 256) {
        // x rows: coalesced float4 read, quantize, LDS transpose, NHWC write
        float scale = 127.0f / Tf;
        int b = blk >> 5, h = blk & 31;
        const float4* x4 = (const float4*)x;
        #pragma unroll
        for (int k = 0; k < 2; ++k) {
            int f = t + k * 256;            // [0,512): ci = f>>3, wq = f&7
            int ci = f >> 3, wq = f & 7;
            float4 v = x4[(b * CIN + ci) * 256 + h * 8 + wq];
            unsigned pack = quantb(v.x, scale) | (quantb(v.y, scale) << 8) |
                            (quantb(v.z, scale) << 16) | (quantb(v.w, scale) << 24);
            lds[ci * 9 + wq] = pack;
        }
        __syncthreads();
        const uint8_t* ldsb = (const uint8_t*)lds;
        unsigned* orow = (unsigned*)(xpad + (((b * PH) + (h + 1)) * PW + 1) * CIN);
        #pragma unroll
        for (int k = 0; k < 2; ++k) {
            int o = t + k * 256;            // [0,512): w = o>>4, c4 = o&15
            int ww_ = o >> 4, c4 = o & 15;
            unsigned d = (unsigned)ldsb[(c4 * 4 + 0) * 36 + ww_]
                       | ((unsigned)ldsb[(c4 * 4 + 1) * 36 + ww_] << 8)
                       | ((unsigned)ldsb[(c4 * 4 + 2) * 36 + ww_] << 16)
                       | ((unsigned)ldsb[(c4 * 4 + 3) * 36 + ww_] << 24);
            orow[o] = d;
        }
    } else if (blk < 328) {
        // weights -> MFMA-B fragment order
        float scale = 127.0f / Tw;
        int tid = (blk - 256) * 256 + t;
        int idx4 = tid * 4;
        int j0 = idx4 & 15;
        int ln = (idx4 >> 4) & 63;
        int f  = idx4 >> 10;          // tap*8 + g
        int g = f & 7;
        int tap = f >> 3;
        int kh = tap / 3, kw = tap - kh * 3;
        int co = g * 16 + (ln & 15);
        int ci0 = (ln >> 4) * 16 + j0;
        unsigned pack = 0;
        #pragma unroll
        for (int c = 0; c < 4; ++c) {
            float v = w[((co * CIN + ci0 + c) * 3 + kh) * 3 + kw];
            pack |= quantb(v, scale) << (8 * c);
        }
        ((unsigned*)wfrag)[tid] = pack;
    } else if (blk < 394) {
        // border zero-fill: 1056 pixels * 16 dwords = 16896 dwords
        int j = (blk - 328) * 256 + t;
        int p = j >> 4, c4 = j & 15;
        int b = p / 132;
        int r = p - b * 132;
        int ih, iw;
        if (r < 34)      { ih = 0;           iw = r; }
        else if (r < 68) { ih = PH - 1;      iw = r - 34; }
        else if (r < 100){ ih = r - 68 + 1;  iw = 0; }
        else             { ih = r - 100 + 1; iw = PW - 1; }
        ((unsigned*)xpad)[((b * PH + ih) * PW + iw) * 16 + c4] = 0u;
    }

    grid.sync();

    // ---------------- phase 3: implicit-GEMM conv (unchanged structure) ----------
    {
        int nb = blk & 1;
        int mb = blk >> 1;
        int b = mb >> 5;
        int oh = mb & 31;
        int mt = wave & 1;            // pixel half (16 pixels)
        int nh2 = wave >> 1;          // cout sub-half
        int row = lane & 15;
        int quad = lane >> 4;

        v4i acc[2];
        acc[0] = (v4i){0, 0, 0, 0};
        acc[1] = (v4i){0, 0, 0, 0};

        const uint8_t* xbase = xpad + (((b * PH + oh) * PW) + mt * 16 + row) * CIN + quad * 16;

        #pragma unroll
        for (int tp = 0; tp < 9; ++tp) {
            const int kh = tp / 3, kw = tp % 3;
            v4i afrag = *(const v4i*)(xbase + (kh * PW + kw) * CIN);
            #pragma unroll
            for (int nt = 0; nt < 2; ++nt) {
                int g = nb * 4 + nh2 * 2 + nt;
                v4i bfrag = *(const v4i*)(wfrag + (((tp * 8 + g) * 64) + lane) * 16);
                acc[nt] = __builtin_amdgcn_mfma_i32_16x16x64_i8(afrag, bfrag, acc[nt], 0, 0, 0);
            }
        }

        float s = (Tf / 127.0f) * (Tw / 127.0f);
        int ow0 = mt * 16 + quad * 4;
        #pragma unroll
        for (int nt = 0; nt < 2; ++nt) {
            int g = nb * 4 + nh2 * 2 + nt;
            int co = g * 16 + row;
            float bb = bias[co];
            v4f o;
            o.x = (float)acc[nt][0] * s + bb;
            o.y = (float)acc[nt][1] * s + bb;
            o.z = (float)acc[nt][2] * s + bb;
            o.w = (float)acc[nt][3] * s + bb;
            __builtin_nontemporal_store(o, (v4f*)(out + (((b * COUT + co) * HH + oh) * WW) + ow0));
        }
    }
}

// =====================================================================
// Fallback (non-cooperative) 3-kernel path — identical to previous best.
// Only used if hipLaunchCooperativeKernel fails at enqueue time.
// =====================================================================
#define WS_TF 0
#define WS_TW 1
#define WS_PART 16
#define QB_X 256
#define QB_W 72

__global__ __launch_bounds__(256) void absmax_zfill(const float* __restrict__ x,
                                                    const float* __restrict__ w,
                                                    float* __restrict__ partials,
                                                    uint8_t* __restrict__ xpad) {
    int blk = blockIdx.x;
    int t = threadIdx.x;

    if (blk >= 144) {
        int j = (blk - 144) * 256 + t;
        int p = j >> 4, c4 = j & 15;
        int b = p / 132;
        int r = p - b * 132;
        int ih, iw;
        if (r < 34)      { ih = 0;           iw = r; }
        else if (r < 68) { ih = PH - 1;      iw = r - 34; }
        else if (r < 100){ ih = r - 68 + 1;  iw = 0; }
        else             { ih = r - 100 + 1; iw = PW - 1; }
        ((unsigned*)xpad)[((b * PH + ih) * PW + iw) * 16 + c4] = 0u;
        return;
    }

    float m = 0.0f;
    if (blk < 128) {
        const float4* p = (const float4*)x;
        int base = blk * 1024 + t;
        #pragma unroll
        for (int k = 0; k < 4; ++k) {
            float4 v = p[base + k * 256];
            m = fmaxf(m, fmaxf(fmaxf(fabsf(v.x), fabsf(v.y)), fmaxf(fabsf(v.z), fabsf(v.w))));
        }
    } else {
        const float4* p = (const float4*)w;
        int wb = blk - 128;
        int base = wb * 1152 + t;
        int end = (wb + 1) * 1152;
        #pragma unroll
        for (int k = 0; k < 5; ++k) {
            int i = base + k * 256;
            if (i < end) {
                float4 v = p[i];
                m = fmaxf(m, fmaxf(fmaxf(fabsf(v.x), fabsf(v.y)), fmaxf(fabsf(v.z), fabsf(v.w))));
            }
        }
    }
    #pragma unroll
    for (int off = 32; off > 0; off >>= 1)
        m = fmaxf(m, __shfl_xor(m, off, 64));
    __shared__ float sm[4];
    int wave = t >> 6;
    if ((t & 63) == 0) sm[wave] = m;
    __syncthreads();
    if (t == 0)
        partials[WS_PART + blk] = fmaxf(fmaxf(sm[0], sm[1]), fmaxf(sm[2], sm[3]));
}

__global__ __launch_bounds__(256) void quant_pack(const float* __restrict__ x,
                                                  const float* __restrict__ w,
                                                  const float* __restrict__ Tf_in,
                                                  const float* __restrict__ Tw_in,
                                                  float* __restrict__ ws_f32,
                                                  uint8_t* __restrict__ xpad,
                                                  uint8_t* __restrict__ wfrag) {
    int blk = blockIdx.x;
    int t = threadIdx.x;
    int lane = t & 63;

    if (blk < QB_X) {
        float m = fmaxf(ws_f32[WS_PART + lane], ws_f32[WS_PART + 64 + lane]);
        #pragma unroll
        for (int off = 32; off > 0; off >>= 1)
            m = fmaxf(m, __shfl_xor(m, off, 64));
        float a = 0.95f * Tf_in[0];
        float bt = 0.05f * m;
        float Tf = a + bt;
        if (blk == 0 && t == 0) ws_f32[WS_TF] = Tf;
        float scale = 127.0f / Tf;

        int b = blk >> 5, h = blk & 31;
        const float4* x4 = (const float4*)x;
        __shared__ unsigned lds[CIN * 9];
        #pragma unroll
        for (int k = 0; k < 2; ++k) {
            int f = t + k * 256;
            int ci = f >> 3, wq = f & 7;
            float4 v = x4[(b * CIN + ci) * 256 + h * 8 + wq];
            unsigned pack = quantb(v.x, scale) | (quantb(v.y, scale) << 8) |
                            (quantb(v.z, scale) << 16) | (quantb(v.w, scale) << 24);
            lds[ci * 9 + wq] = pack;
        }
        __syncthreads();
        const uint8_t* ldsb = (const uint8_t*)lds;
        unsigned* orow = (unsigned*)(xpad + (((b * PH) + (h + 1)) * PW + 1) * CIN);
        #pragma unroll
        for (int k = 0; k < 2; ++k) {
            int o = t + k * 256;
            int ww_ = o >> 4, c4 = o & 15;
            unsigned d = (unsigned)ldsb[(c4 * 4 + 0) * 36 + ww_]
                       | ((unsigned)ldsb[(c4 * 4 + 1) * 36 + ww_] << 8)
                       | ((unsigned)ldsb[(c4 * 4 + 2) * 36 + ww_] << 16)
                       | ((unsigned)ldsb[(c4 * 4 + 3) * 36 + ww_] << 24);
            orow[o] = d;
        }
    } else {
        float m = ws_f32[WS_PART + 128 + (lane & 15)];
        #pragma unroll
        for (int off = 32; off > 0; off >>= 1)
            m = fmaxf(m, __shfl_xor(m, off, 64));
        float a = 0.95f * Tw_in[0];
        float bt = 0.05f * m;
        float Tw = a + bt;
        if (blk == QB_X && t == 0) ws_f32[WS_TW] = Tw;
        float scale = 127.0f / Tw;

        int tid = (blk - QB_X) * 256 + t;
        int idx4 = tid * 4;
        int j0 = idx4 & 15;
        int ln = (idx4 >> 4) & 63;
        int f  = idx4 >> 10;
        int g = f & 7;
        int tap = f >> 3;
        int kh = tap / 3, kw = tap - kh * 3;
        int co = g * 16 + (ln & 15);
        int ci0 = (ln >> 4) * 16 + j0;
        unsigned pack = 0;
        #pragma unroll
        for (int c = 0; c < 4; ++c) {
            float v = w[((co * CIN + ci0 + c) * 3 + kh) * 3 + kw];
            pack |= quantb(v, scale) << (8 * c);
        }
        ((unsigned*)wfrag)[tid] = pack;
    }
}

__global__ __launch_bounds__(256, 2) void conv_mfma(const uint8_t* __restrict__ xpad,
                                                    const uint8_t* __restrict__ wfrag,
                                                    const float* __restrict__ bias,
                                                    const float* __restrict__ ws_f32,
                                                    float* __restrict__ out) {
    int blk = blockIdx.x;
    int nb = blk & 1;
    int mb = blk >> 1;
    int b = mb >> 5;
    int oh = mb & 31;
    int wave = threadIdx.x >> 6;
    int lane = threadIdx.x & 63;
    int mt = wave & 1;
    int nh2 = wave >> 1;
    int row = lane & 15;
    int quad = lane >> 4;

    v4i acc[2];
    acc[0] = (v4i){0, 0, 0, 0};
    acc[1] = (v4i){0, 0, 0, 0};

    const uint8_t* xbase = xpad + (((b * PH + oh) * PW) + mt * 16 + row) * CIN + quad * 16;

    #pragma unroll
    for (int tp = 0; tp < 9; ++tp) {
        const int kh = tp / 3, kw = tp % 3;
        v4i afrag = *(const v4i*)(xbase + (kh * PW + kw) * CIN);
        #pragma unroll
        for (int nt = 0; nt < 2; ++nt) {
            int g = nb * 4 + nh2 * 2 + nt;
            v4i bfrag = *(const v4i*)(wfrag + (((tp * 8 + g) * 64) + lane) * 16);
            acc[nt] = __builtin_amdgcn_mfma_i32_16x16x64_i8(afrag, bfrag, acc[nt], 0, 0, 0);
        }
    }

    float Tf = ws_f32[WS_TF];
    float Tw = ws_f32[WS_TW];
    float s = (Tf / 127.0f) * (Tw / 127.0f);
    int ow0 = mt * 16 + quad * 4;
    #pragma unroll
    for (int nt = 0; nt < 2; ++nt) {
        int g = nb * 4 + nh2 * 2 + nt;
        int co = g * 16 + row;
        float bb = bias[co];
        v4f o;
        o.x = (float)acc[nt][0] * s + bb;
        o.y = (float)acc[nt][1] * s + bb;
        o.z = (float)acc[nt][2] * s + bb;
        o.w = (float)acc[nt][3] * s + bb;
        __builtin_nontemporal_store(o, (v4f*)(out + (((b * COUT + co) * HH + oh) * WW) + ow0));
    }
}

extern "C" void kernel_launch(void* const* d_in, const int* in_sizes, int n_in,
                              void* d_out, int out_size, void* d_ws, size_t ws_size,
                              hipStream_t stream) {
    const float* x         = (const float*)d_in[0];
    const float* weight    = (const float*)d_in[1];
    const float* bias      = (const float*)d_in[2];
    const float* T_feature = (const float*)d_in[5];
    const float* T_weight  = (const float*)d_in[6];

    float*   ws_f32 = (float*)d_ws;
    uint8_t* xpad   = (uint8_t*)d_ws + XPAD_OFF;
    uint8_t* wfrag  = (uint8_t*)d_ws + WFRAG_OFF;
    float*   out    = (float*)d_out;

    void* args[] = {(void*)&x, (void*)&weight, (void*)&bias, (void*)&T_feature,
                    (void*)&T_weight, (void*)&ws_f32, (void*)&xpad, (void*)&wfrag,
                    (void*)&out};
    hipError_t err = hipLaunchCooperativeKernel(reinterpret_cast<const void*>(fused_all),
                                                dim3(512), dim3(256), args, 0u, stream);
    if (err != hipSuccess) {
        // fallback: previous 3-kernel path
        absmax_zfill<<<210, 256, 0, stream>>>(x, weight, ws_f32, xpad);
        quant_pack<<<QB_X + QB_W, 256, 0, stream>>>(x, weight, T_feature, T_weight,
                                                    ws_f32, xpad, wfrag);
        conv_mfma<<<512, 256, 0, stream>>>(xpad, wfrag, bias, ws_f32, out);
    }
}

// Round 2
// 86.540 us; speedup vs baseline: 2.1454x; 2.1454x over previous
//
#include <hip/hip_runtime.h>
#include <cstdint>

#define BATCH 8
#define CIN 64
#define COUT 128
#define HH 32
#define WW 32

typedef int v4i __attribute__((ext_vector_type(4)));
typedef float v4f __attribute__((ext_vector_type(4)));

// ---------------- workspace layout ----------------
// f32[1]       : Tw (written by prep w-blocks)
// f32[16..143] : x absmax partials (128 blocks)
// byte 4096    : wfrag int8 MFMA-B-swizzled [9][8][64][16] = 73728 B
#define WS_TW 1
#define WS_PX 16
#define WFRAG_OFF 4096

__device__ __forceinline__ unsigned quantb(float v, float scale) {
    float q = rintf(v * scale);
    q = fminf(fmaxf(q, -128.0f), 127.0f);
    return ((unsigned)(int)q) & 255u;
}

// =====================================================================
// kernel 1: x absmax partials (blocks 0..127)
//         + w full-absmax + quantize -> wfrag (blocks 128..145)
// w is only 288 KB: each w-block redundantly reads ALL of w, so Tw is
// block-local and no inter-block sync is needed anywhere in this kernel.
// =====================================================================
__global__ __launch_bounds__(256) void prep(const float* __restrict__ x,
                                            const float* __restrict__ w,
                                            const float* __restrict__ Tw_in,
                                            float* __restrict__ ws_f32,
                                            uint8_t* __restrict__ wfrag) {
    int blk = blockIdx.x;
    int t = threadIdx.x;
    int lane = t & 63;
    int wave = t >> 6;
    __shared__ float sm[4];

    if (blk < 128) {
        // ---- x absmax partials: 128 blocks * 256 t * 4 float4 = 2 MB ----
        const float4* p = (const float4*)x;
        int base = blk * 1024 + t;
        float m = 0.0f;
        #pragma unroll
        for (int k = 0; k < 4; ++k) {
            float4 v = p[base + k * 256];
            m = fmaxf(m, fmaxf(fmaxf(fabsf(v.x), fabsf(v.y)), fmaxf(fabsf(v.z), fabsf(v.w))));
        }
        #pragma unroll
        for (int off = 32; off > 0; off >>= 1)
            m = fmaxf(m, __shfl_xor(m, off, 64));
        if (lane == 0) sm[wave] = m;
        __syncthreads();
        if (t == 0)
            ws_f32[WS_PX + blk] = fmaxf(fmaxf(sm[0], sm[1]), fmaxf(sm[2], sm[3]));
    } else {
        // ---- w path: full absmax (redundant per block) + quantize slice ----
        const float4* w4 = (const float4*)w;
        float m = 0.0f;
        #pragma unroll 8
        for (int i = 0; i < 72; ++i) {        // 72*256 float4 = all 73728 floats
            float4 v = w4[t + i * 256];
            m = fmaxf(m, fmaxf(fmaxf(fabsf(v.x), fabsf(v.y)), fmaxf(fabsf(v.z), fabsf(v.w))));
        }
        #pragma unroll
        for (int off = 32; off > 0; off >>= 1)
            m = fmaxf(m, __shfl_xor(m, off, 64));
        if (lane == 0) sm[wave] = m;
        __syncthreads();
        float Mw = fmaxf(fmaxf(sm[0], sm[1]), fmaxf(sm[2], sm[3]));
        float Tw = 0.95f * Tw_in[0] + 0.05f * Mw;
        if (blk == 128 && t == 0) ws_f32[WS_TW] = Tw;
        float scale = 127.0f / Tw;

        int wb = blk - 128;                   // 18 blocks * 1024 dwords = 73728 B
        #pragma unroll
        for (int k = 0; k < 4; ++k) {
            int d = wb * 1024 + k * 256 + t;  // dword id in wfrag
            int idx4 = d * 4;
            int j0 = idx4 & 15;
            int ln = (idx4 >> 4) & 63;
            int f  = idx4 >> 10;              // tap*8 + g
            int g = f & 7;
            int tap = f >> 3;
            int kh = tap / 3, kw = tap - kh * 3;
            int co = g * 16 + (ln & 15);
            int ci0 = (ln >> 4) * 16 + j0;
            unsigned pack = 0;
            #pragma unroll
            for (int c = 0; c < 4; ++c) {
                float v = w[((co * CIN + ci0 + c) * 3 + kh) * 3 + kw];
                pack |= quantb(v, scale) << (8 * c);
            }
            ((unsigned*)wfrag)[d] = pack;
        }
    }
}

// =====================================================================
// kernel 2: fused x-quantize (into LDS halo tile) + implicit-GEMM conv.
// 512 blocks: nb = blk&1 (cout half), mb = blk>>1 -> (b, oh).
// Per block: reduce 128 x-partials -> Tf; quantize 3x34x64 int8 tile
// from x (L2/L3-resident) into LDS; 9-tap MFMA loop; scaled epilogue.
// No xpad global round-trip, no zfill.
// =====================================================================
__global__ __launch_bounds__(256, 2) void conv_fused(const float* __restrict__ x,
                                                     const uint8_t* __restrict__ wfrag,
                                                     const float* __restrict__ bias,
                                                     const float* __restrict__ Tf_in,
                                                     const float* __restrict__ ws_f32,
                                                     float* __restrict__ out) {
    int blk = blockIdx.x;
    int t = threadIdx.x;
    int lane = t & 63;
    int wave = t >> 6;
    int nb = blk & 1;
    int mb = blk >> 1;
    int b = mb >> 5;
    int oh = mb & 31;

    __shared__ unsigned stg[3 * 64 * 9];     // staging: [(r*64+ci)*9 + wq], pitch 9 dwords
    __shared__ unsigned tile[3 * 34 * 16];   // int8 tile: byte ((r*34+px)*64 + ci)

    // ---- Tf from partials (per-wave redundant, no barrier needed) ----
    float mx = fmaxf(ws_f32[WS_PX + lane], ws_f32[WS_PX + 64 + lane]);
    #pragma unroll
    for (int off = 32; off > 0; off >>= 1)
        mx = fmaxf(mx, __shfl_xor(mx, off, 64));
    float Tf = 0.95f * Tf_in[0] + 0.05f * mx;
    float Tw = ws_f32[WS_TW];
    float scale = 127.0f / Tf;

    // ---- zero tile (borders + OOB rows stay zero) ----
    #pragma unroll
    for (int k = 0; k < 7; ++k) {
        int i = t + k * 256;
        if (i < 3 * 34 * 16) tile[i] = 0u;
    }

    // ---- stage 1: coalesced x read + quantize -> stg ----
    // 1536 float4 jobs: f -> (ci = f/24, r = (f%24)>>3, wq = f&7)
    const float4* x4 = (const float4*)x;
    #pragma unroll
    for (int k = 0; k < 6; ++k) {
        int f = t + k * 256;
        int ci = f / 24;
        int rem = f - ci * 24;
        int r = rem >> 3, wq = rem & 7;
        int ih = oh - 1 + r;
        if (ih >= 0 && ih < HH) {
            float4 v = x4[(b * CIN + ci) * 256 + ih * 8 + wq];
            unsigned pack = quantb(v.x, scale) | (quantb(v.y, scale) << 8) |
                            (quantb(v.z, scale) << 16) | (quantb(v.w, scale) << 24);
            stg[(r * 64 + ci) * 9 + wq] = pack;
        }
    }
    __syncthreads();

    // ---- stage 2: byte transpose stg -> tile interior (px 1..32) ----
    const uint8_t* stgb = (const uint8_t*)stg;
    #pragma unroll
    for (int k = 0; k < 6; ++k) {
        int o = t + k * 256;                 // (r, ww_, c4)
        int c4 = o & 15;
        int q = o >> 4;
        int ww_ = q & 31;
        int r = q >> 5;
        int ih = oh - 1 + r;
        if (ih >= 0 && ih < HH) {
            unsigned d = (unsigned)stgb[(r * 64 + c4 * 4 + 0) * 36 + ww_]
                       | ((unsigned)stgb[(r * 64 + c4 * 4 + 1) * 36 + ww_] << 8)
                       | ((unsigned)stgb[(r * 64 + c4 * 4 + 2) * 36 + ww_] << 16)
                       | ((unsigned)stgb[(r * 64 + c4 * 4 + 3) * 36 + ww_] << 24);
            tile[(r * 34 + ww_ + 1) * 16 + c4] = d;
        }
    }
    __syncthreads();

    // ---- conv: 9-tap MFMA from LDS tile + global wfrag (L2-hot) ----
    int mt = wave & 1;            // pixel half (16 pixels)
    int nh2 = wave >> 1;          // cout sub-half
    int row = lane & 15;
    int quad = lane >> 4;
    int px0 = mt * 16 + row;

    v4i acc[2];
    acc[0] = (v4i){0, 0, 0, 0};
    acc[1] = (v4i){0, 0, 0, 0};

    const uint8_t* tb = (const uint8_t*)tile;

    #pragma unroll
    for (int tp = 0; tp < 9; ++tp) {
        const int kh = tp / 3, kw = tp % 3;
        v4i afrag = *(const v4i*)(tb + ((kh * 34 + px0 + kw) * 64) + quad * 16);
        #pragma unroll
        for (int nt = 0; nt < 2; ++nt) {
            int g = nb * 4 + nh2 * 2 + nt;
            v4i bfrag = *(const v4i*)(wfrag + (((tp * 8 + g) * 64) + lane) * 16);
            acc[nt] = __builtin_amdgcn_mfma_i32_16x16x64_i8(afrag, bfrag, acc[nt], 0, 0, 0);
        }
    }

    float s = (Tf / 127.0f) * (Tw / 127.0f);
    int ow0 = mt * 16 + quad * 4;
    #pragma unroll
    for (int nt = 0; nt < 2; ++nt) {
        int g = nb * 4 + nh2 * 2 + nt;
        int co = g * 16 + row;
        float bb = bias[co];
        v4f o;
        o.x = (float)acc[nt][0] * s + bb;
        o.y = (float)acc[nt][1] * s + bb;
        o.z = (float)acc[nt][2] * s + bb;
        o.w = (float)acc[nt][3] * s + bb;
        __builtin_nontemporal_store(o, (v4f*)(out + (((b * COUT + co) * HH + oh) * WW) + ow0));
    }
}

extern "C" void kernel_launch(void* const* d_in, const int* in_sizes, int n_in,
                              void* d_out, int out_size, void* d_ws, size_t ws_size,
                              hipStream_t stream) {
    const float* x         = (const float*)d_in[0];
    const float* weight    = (const float*)d_in[1];
    const float* bias      = (const float*)d_in[2];
    const float* T_feature = (const float*)d_in[5];
    const float* T_weight  = (const float*)d_in[6];

    float*   ws_f32 = (float*)d_ws;
    uint8_t* wfrag  = (uint8_t*)d_ws + WFRAG_OFF;

    prep<<<146, 256, 0, stream>>>(x, weight, T_weight, ws_f32, wfrag);
    conv_fused<<<512, 256, 0, stream>>>(x, wfrag, bias, T_feature, ws_f32,
                                        (float*)d_out);
}

// Round 3
// 78.512 us; speedup vs baseline: 2.3647x; 1.1023x over previous
//
#include <hip/hip_runtime.h>
#include <cstdint>

#define BATCH 8
#define CIN 64
#define COUT 128
#define HH 32
#define WW 32

typedef int v4i __attribute__((ext_vector_type(4)));
typedef float v4f __attribute__((ext_vector_type(4)));

// ---------------- workspace layout ----------------
// f32[1]       : Tw (written by prep w-block 0)
// f32[16..143] : x absmax partials (128 x-blocks)
// byte 4096    : wfrag int8 MFMA-B-swizzled [9][8][64][16] = 73728 B
#define WS_TW 1
#define WS_PX 16
#define WFRAG_OFF 4096

// LDS tile: 3 rows x 34 px x 72 B/pixel (18 dwords: 16 data + 2 pad)
#define TPITCH 18

__device__ __forceinline__ unsigned quantb(float v, float scale) {
    float q = rintf(v * scale);
    q = fminf(fmaxf(q, -128.0f), 127.0f);
    return ((unsigned)(int)q) & 255u;
}

// =====================================================================
// kernel 1: w full-absmax + quantize -> wfrag (blocks 0..17, longest first)
//         + x absmax partials (blocks 18..145)
// w is 288 KB: each w-block redundantly reads all of w -> Tw is
// block-local; no inter-block dependency anywhere in this kernel.
// =====================================================================
__global__ __launch_bounds__(256) void prep(const float* __restrict__ x,
                                            const float* __restrict__ w,
                                            const float* __restrict__ Tw_in,
                                            float* __restrict__ ws_f32,
                                            uint8_t* __restrict__ wfrag) {
    int blk = blockIdx.x;
    int t = threadIdx.x;
    int lane = t & 63;
    int wave = t >> 6;
    __shared__ float sm[4];

    if (blk >= 18) {
        // ---- x absmax partials: 128 blocks * 256 t * 4 float4 = 2 MB ----
        const float4* p = (const float4*)x;
        int xb = blk - 18;
        int base = xb * 1024 + t;
        float m = 0.0f;
        #pragma unroll
        for (int k = 0; k < 4; ++k) {
            float4 v = p[base + k * 256];
            m = fmaxf(m, fmaxf(fmaxf(fabsf(v.x), fabsf(v.y)), fmaxf(fabsf(v.z), fabsf(v.w))));
        }
        #pragma unroll
        for (int off = 32; off > 0; off >>= 1)
            m = fmaxf(m, __shfl_xor(m, off, 64));
        if (lane == 0) sm[wave] = m;
        __syncthreads();
        if (t == 0)
            ws_f32[WS_PX + xb] = fmaxf(fmaxf(sm[0], sm[1]), fmaxf(sm[2], sm[3]));
    } else {
        // ---- w path: full absmax (4 split accumulators) + quantize slice ----
        const float4* w4 = (const float4*)w;
        float m0 = 0.0f, m1 = 0.0f, m2 = 0.0f, m3 = 0.0f;
        #pragma unroll
        for (int i = 0; i < 72; i += 4) {
            float4 a = w4[t + (i + 0) * 256];
            float4 bv = w4[t + (i + 1) * 256];
            float4 c = w4[t + (i + 2) * 256];
            float4 d = w4[t + (i + 3) * 256];
            m0 = fmaxf(m0, fmaxf(fmaxf(fabsf(a.x), fabsf(a.y)), fmaxf(fabsf(a.z), fabsf(a.w))));
            m1 = fmaxf(m1, fmaxf(fmaxf(fabsf(bv.x), fabsf(bv.y)), fmaxf(fabsf(bv.z), fabsf(bv.w))));
            m2 = fmaxf(m2, fmaxf(fmaxf(fabsf(c.x), fabsf(c.y)), fmaxf(fabsf(c.z), fabsf(c.w))));
            m3 = fmaxf(m3, fmaxf(fmaxf(fabsf(d.x), fabsf(d.y)), fmaxf(fabsf(d.z), fabsf(d.w))));
        }
        float m = fmaxf(fmaxf(m0, m1), fmaxf(m2, m3));
        #pragma unroll
        for (int off = 32; off > 0; off >>= 1)
            m = fmaxf(m, __shfl_xor(m, off, 64));
        if (lane == 0) sm[wave] = m;
        __syncthreads();
        float Mw = fmaxf(fmaxf(sm[0], sm[1]), fmaxf(sm[2], sm[3]));
        float Tw = 0.95f * Tw_in[0] + 0.05f * Mw;
        if (blk == 0 && t == 0) ws_f32[WS_TW] = Tw;
        float scale = 127.0f / Tw;

        int wb = blk;                         // 18 blocks * 1024 dwords = 73728 B
        #pragma unroll
        for (int k = 0; k < 4; ++k) {
            int d = wb * 1024 + k * 256 + t;  // dword id in wfrag
            int idx4 = d * 4;
            int j0 = idx4 & 15;
            int ln = (idx4 >> 4) & 63;
            int f  = idx4 >> 10;              // tap*8 + g
            int g = f & 7;
            int tap = f >> 3;
            int kh = tap / 3, kw = tap - kh * 3;
            int co = g * 16 + (ln & 15);
            int ci0 = (ln >> 4) * 16 + j0;
            unsigned pack = 0;
            #pragma unroll
            for (int c = 0; c < 4; ++c) {
                float v = w[((co * CIN + ci0 + c) * 3 + kh) * 3 + kw];
                pack |= quantb(v, scale) << (8 * c);
            }
            ((unsigned*)wfrag)[d] = pack;
        }
    }
}

// =====================================================================
// kernel 2: fused x-quantize + implicit-GEMM conv. 512 blocks (b,oh,nb).
// Per block: Tf from partials (shuffle, no barrier); quantize own 3-row
// halo into NHWC LDS tile via in-register 4x4 byte transpose (v_perm) +
// direct conflict-balanced ds_write_b32; ONE barrier; 9-tap MFMA loop.
// =====================================================================
__global__ __launch_bounds__(256, 2) void conv_fused(const float* __restrict__ x,
                                                     const uint8_t* __restrict__ wfrag,
                                                     const float* __restrict__ bias,
                                                     const float* __restrict__ Tf_in,
                                                     const float* __restrict__ ws_f32,
                                                     float* __restrict__ out) {
    int blk = blockIdx.x;
    int t = threadIdx.x;
    int lane = t & 63;
    int wave = t >> 6;
    int nb = blk & 1;
    int mb = blk >> 1;
    int b = mb >> 5;
    int oh = mb & 31;

    __shared__ unsigned tile[3 * 34 * TPITCH];   // 7344 B

    // ---- Tf from partials (per-wave redundant; issue loads first) ----
    float p0 = ws_f32[WS_PX + lane];
    float p1 = ws_f32[WS_PX + 64 + lane];
    float Tw = ws_f32[WS_TW];

    // ---- zero-fill: borders always (96 dw); OOB row only for oh 0/31 ----
    if (t < 96) {
        int rr = t >> 5;
        int rest = t & 31;
        int side = rest >> 4;
        int kk = rest & 15;
        tile[(rr * 34 + side * 33) * TPITCH + kk] = 0u;
    }
    if (oh == 0 || oh == 31) {
        int rbad = (oh == 0) ? 0 : 2;
        #pragma unroll
        for (int k = 0; k < 3; ++k) {
            int i = t + k * 256;
            if (i < 544) {
                int px = i >> 4, kk = i & 15;
                tile[(rbad * 34 + px) * TPITCH + kk] = 0u;
            }
        }
    }

    float mx = fmaxf(p0, p1);
    #pragma unroll
    for (int off = 32; off > 0; off >>= 1)
        mx = fmaxf(mx, __shfl_xor(mx, off, 64));
    float Tf = 0.95f * Tf_in[0] + 0.05f * mx;
    float scale = 127.0f / Tf;

    // ---- quantize + in-register 4x4 transpose + direct NHWC writes ----
    // 384 jobs: j -> (r = j>>7, wq = (j&127)>>4, g4 = j&15)
    const float4* x4 = (const float4*)x;
    #pragma unroll
    for (int k = 0; k < 2; ++k) {
        int j = t + k * 256;
        if (j < 384) {
            int r = j >> 7;
            int rem = j & 127;
            int wq = rem >> 4;
            int g4 = rem & 15;
            int ih = oh - 1 + r;
            if (ih >= 0 && ih < HH) {
                int xb = (b * CIN + g4 * 4) * 256 + ih * 8 + wq;
                float4 v0 = x4[xb];
                float4 v1 = x4[xb + 256];
                float4 v2 = x4[xb + 512];
                float4 v3 = x4[xb + 768];
                unsigned P0 = quantb(v0.x, scale) | (quantb(v0.y, scale) << 8) |
                              (quantb(v0.z, scale) << 16) | (quantb(v0.w, scale) << 24);
                unsigned P1 = quantb(v1.x, scale) | (quantb(v1.y, scale) << 8) |
                              (quantb(v1.z, scale) << 16) | (quantb(v1.w, scale) << 24);
                unsigned P2 = quantb(v2.x, scale) | (quantb(v2.y, scale) << 8) |
                              (quantb(v2.z, scale) << 16) | (quantb(v2.w, scale) << 24);
                unsigned P3 = quantb(v3.x, scale) | (quantb(v3.y, scale) << 8) |
                              (quantb(v3.z, scale) << 16) | (quantb(v3.w, scale) << 24);
                // 4x4 byte transpose: D[bi].byte[c] = P[c].byte[bi]
                unsigned Q0 = __builtin_amdgcn_perm(P1, P0, 0x05040100u); // [P0b0,P0b1,P1b0,P1b1]
                unsigned Q1 = __builtin_amdgcn_perm(P1, P0, 0x07060302u); // [P0b2,P0b3,P1b2,P1b3]
                unsigned Q2 = __builtin_amdgcn_perm(P3, P2, 0x05040100u);
                unsigned Q3 = __builtin_amdgcn_perm(P3, P2, 0x07060302u);
                unsigned D0 = __builtin_amdgcn_perm(Q2, Q0, 0x06040200u); // [P0b0,P1b0,P2b0,P3b0]
                unsigned D1 = __builtin_amdgcn_perm(Q2, Q0, 0x07050301u);
                unsigned D2 = __builtin_amdgcn_perm(Q3, Q1, 0x06040200u);
                unsigned D3 = __builtin_amdgcn_perm(Q3, Q1, 0x07050301u);
                int base = (r * 34 + wq * 4 + 1) * TPITCH + g4;
                tile[base]              = D0;
                tile[base + TPITCH]     = D1;
                tile[base + 2 * TPITCH] = D2;
                tile[base + 3 * TPITCH] = D3;
            }
        }
    }
    __syncthreads();

    // ---- conv: 9-tap MFMA from LDS tile + global wfrag (L2-hot) ----
    int mt = wave & 1;            // pixel half (16 pixels)
    int nh2 = wave >> 1;          // cout sub-half
    int row = lane & 15;
    int quad = lane >> 4;
    int px0 = mt * 16 + row;

    v4i acc[2];
    acc[0] = (v4i){0, 0, 0, 0};
    acc[1] = (v4i){0, 0, 0, 0};

    const int2* tl2 = (const int2*)tile;

    #pragma unroll
    for (int tp = 0; tp < 9; ++tp) {
        const int kh = tp / 3, kw = tp % 3;
        int d = ((kh * 34) + px0 + kw) * TPITCH + quad * 4;   // even -> 8B aligned
        int2 lo = tl2[(d >> 1)];
        int2 hi = tl2[(d >> 1) + 1];
        v4i afrag = (v4i){lo.x, lo.y, hi.x, hi.y};
        #pragma unroll
        for (int nt = 0; nt < 2; ++nt) {
            int g = nb * 4 + nh2 * 2 + nt;
            v4i bfrag = *(const v4i*)(wfrag + (((tp * 8 + g) * 64) + lane) * 16);
            acc[nt] = __builtin_amdgcn_mfma_i32_16x16x64_i8(afrag, bfrag, acc[nt], 0, 0, 0);
        }
    }

    float s = (Tf / 127.0f) * (Tw / 127.0f);
    int ow0 = mt * 16 + quad * 4;
    #pragma unroll
    for (int nt = 0; nt < 2; ++nt) {
        int g = nb * 4 + nh2 * 2 + nt;
        int co = g * 16 + row;
        float bb = bias[co];
        v4f o;
        o.x = (float)acc[nt][0] * s + bb;
        o.y = (float)acc[nt][1] * s + bb;
        o.z = (float)acc[nt][2] * s + bb;
        o.w = (float)acc[nt][3] * s + bb;
        __builtin_nontemporal_store(o, (v4f*)(out + (((b * COUT + co) * HH + oh) * WW) + ow0));
    }
}

extern "C" void kernel_launch(void* const* d_in, const int* in_sizes, int n_in,
                              void* d_out, int out_size, void* d_ws, size_t ws_size,
                              hipStream_t stream) {
    const float* x         = (const float*)d_in[0];
    const float* weight    = (const float*)d_in[1];
    const float* bias      = (const float*)d_in[2];
    const float* T_feature = (const float*)d_in[5];
    const float* T_weight  = (const float*)d_in[6];

    float*   ws_f32 = (float*)d_ws;
    uint8_t* wfrag  = (uint8_t*)d_ws + WFRAG_OFF;

    prep<<<146, 256, 0, stream>>>(x, weight, T_weight, ws_f32, wfrag);
    conv_fused<<<512, 256, 0, stream>>>(x, wfrag, bias, T_feature, ws_f32,
                                        (float*)d_out);
}